// Round 2
// baseline (9225.787 us; speedup 1.0000x reference)
//
#include <hip/hip_runtime.h>
#include <hip/hip_bf16.h>

typedef __hip_bfloat16  bf16;
typedef __hip_bfloat162 bf162;

// Problem constants (B,C,H,W) = (4,64,192,320)
#define Bb  4
#define Cc  64
#define Hh  192
#define Ww  320
#define HWc (Hh*Ww)          // 61440
#define BHW (Bb*HWc)         // 245760

__device__ __forceinline__ float to_f(float x)  { return x; }
__device__ __forceinline__ float to_f(bf16 x)   { return __bfloat162float(x); }

__device__ __forceinline__ void store2(float* p, float a, float b) {
    *(float2*)p = make_float2(a, b);
}
__device__ __forceinline__ void store2(bf16* p, float a, float b) {
    bf162 t; t.x = __float2bfloat16(a); t.y = __float2bfloat16(b);
    *(bf162*)p = t;
}

// ---------------------------------------------------------------------------
// zero-fill (harness poisons d_ws with 0xAA every run)
// ---------------------------------------------------------------------------
__global__ void zero_kernel(float4* __restrict__ p, int n4) {
    int t = blockIdx.x * 256 + threadIdx.x;
    if (t < n4) p[t] = make_float4(0.f, 0.f, 0.f, 0.f);
}

// ---------------------------------------------------------------------------
// softsplat scatter: acc layout [b][65][H*W] fp32, channel 64 = splatted ones
// ---------------------------------------------------------------------------
__global__ void splat_kernel(const float* __restrict__ feat,
                             const float* __restrict__ flow,   // last_flow (B,4,H,W)
                             int flow_ch0, float scale,
                             float* __restrict__ acc) {
    int t = blockIdx.x * 256 + threadIdx.x;
    if (t >= BHW) return;
    int b = t / HWc;
    int p = t - b * HWc;
    int x = p % Ww, y = p / Ww;

    const float* fl = flow + (size_t)b * 4 * HWc;
    float u = fl[flow_ch0 * HWc + p] * scale;
    float v = fl[(flow_ch0 + 1) * HWc + p] * scale;
    float txf = (float)x + u;
    float tyf = (float)y + v;
    float x0f = floorf(txf), y0f = floorf(tyf);
    int ix0 = (int)x0f, iy0 = (int)y0f;
    float wx1 = txf - x0f, wx0 = (x0f + 1.0f) - txf;
    float wy1 = tyf - y0f, wy0 = (y0f + 1.0f) - tyf;

    float wgt[4] = { wx0 * wy0, wx1 * wy0, wx0 * wy1, wx1 * wy1 };
    int   xs[4]  = { ix0, ix0 + 1, ix0,     ix0 + 1 };
    int   ys[4]  = { iy0, iy0,     iy0 + 1, iy0 + 1 };
    bool  val[4];
    int   idx[4];
#pragma unroll
    for (int k = 0; k < 4; k++) {
        val[k] = (xs[k] >= 0) && (xs[k] < Ww) && (ys[k] >= 0) && (ys[k] < Hh);
        idx[k] = ys[k] * Ww + xs[k];
    }

    float* accb = acc + (size_t)b * 65 * HWc;
    const float* fb = feat + (size_t)b * Cc * HWc;
    for (int c = 0; c < Cc; c++) {
        float fv = fb[c * HWc + p];
#pragma unroll
        for (int k = 0; k < 4; k++)
            if (val[k]) atomicAdd(&accb[c * HWc + idx[k]], fv * wgt[k]);
    }
#pragma unroll
    for (int k = 0; k < 4; k++)
        if (val[k]) atomicAdd(&accb[64 * HWc + idx[k]], wgt[k]);
}

// ---------------------------------------------------------------------------
// normalize + convert to bf16 [b][64][HW]; blockIdx.y picks (acc0->f0h)/(acc1->f1h)
// ---------------------------------------------------------------------------
__global__ void normconv_kernel(const float* __restrict__ acc0,
                                const float* __restrict__ acc1,
                                bf16* __restrict__ f0h, bf16* __restrict__ f1h) {
    int t = blockIdx.x * 256 + threadIdx.x;
    if (t >= BHW) return;
    const float* acc = (blockIdx.y == 0) ? acc0 : acc1;
    bf16* outp       = (blockIdx.y == 0) ? f0h  : f1h;
    int b = t / HWc;
    int p = t - b * HWc;
    const float* accb = acc + (size_t)b * 65 * HWc;
    float n = accb[64 * HWc + p];
    float inv = (n == 0.0f) ? 1.0f : 1.0f / n;
    bf16* ob = outp + (size_t)b * 64 * HWc;
    for (int c = 0; c < Cc; c++)
        ob[c * HWc + p] = __float2bfloat16(accb[c * HWc + p] * inv);
}

// ---------------------------------------------------------------------------
// correlation + lrelu: vol[b][d][p], d=(dy+4)*9+(dx+4); bf16 in, bf16 out
// ---------------------------------------------------------------------------
__global__ __launch_bounds__(256) void corr_kernel(const bf16* __restrict__ f0a,
                                                   const bf16* __restrict__ f1a,
                                                   bf16* __restrict__ vol) {
    int t = blockIdx.x * 256 + threadIdx.x;
    if (t >= BHW) return;
    int b = t / HWc;
    int p = t - b * HWc;
    int x = p % Ww, y = p / Ww;

    const bf16* f0 = f0a + (size_t)b * 64 * HWc + p;
    const bf16* f1b = f1a + (size_t)b * 64 * HWc;

    float f0r[64];
#pragma unroll
    for (int c = 0; c < 64; c++) f0r[c] = to_f(f0[c * HWc]);

    bf16* vout = vol + (size_t)b * 81 * HWc + p;
    for (int dy = -4; dy <= 4; dy++) {
        int yy = y + dy;
        bool rowok = (yy >= 0) && (yy < Hh);
        for (int dx = -4; dx <= 4; dx++) {
            int xx = x + dx;
            float s = 0.0f;
            if (rowok && xx >= 0 && xx < Ww) {
                const bf16* f1p = f1b + yy * Ww + xx;
#pragma unroll
                for (int c = 0; c < 64; c++) s += f0r[c] * to_f(f1p[c * HWc]);
            }
            s *= (1.0f / 64.0f);
            s = (s > 0.0f) ? s : 0.1f * s;
            int d = (dy + 4) * 9 + (dx + 4);
            vout[d * HWc] = __float2bfloat16(s);
        }
    }
}

// ---------------------------------------------------------------------------
// conv1: 1x1, 277 -> 160, lrelu. Virtual concat:
// [vol(81,bf16), f0h(64,bf16), f1h(64,bf16), last_feat(64,f32), last_flow(4,f32)]
// 256 threads x 2 px; blockIdx.y = 16-output chunk. Output bf16.
// ---------------------------------------------------------------------------
__global__ __launch_bounds__(256) void conv1_kernel(
    const bf16* __restrict__ vol, const bf16* __restrict__ f0h,
    const bf16* __restrict__ f1h, const float* __restrict__ lastfeat,
    const float* __restrict__ lastflow, const float* __restrict__ w,
    const float* __restrict__ bias, bf16* __restrict__ out) {
    __shared__ float wl[16 * 277];
    int o0 = blockIdx.y * 16;
    for (int idx = threadIdx.x; idx < 16 * 277; idx += 256)
        wl[idx] = w[(o0 + idx / 277) * 277 + (idx % 277)];
    __syncthreads();

    int p0 = blockIdx.x * 512 + threadIdx.x * 2;
    int b = p0 / HWc;
    int pb = p0 - b * HWc;

    float acc[16][2];
#pragma unroll
    for (int j = 0; j < 16; j++) {
        float bv = bias[o0 + j];
        acc[j][0] = bv; acc[j][1] = bv;
    }

    const bf16* segb[3] = {
        vol + (size_t)b * 81 * HWc + pb,
        f0h + (size_t)b * 64 * HWc + pb,
        f1h + (size_t)b * 64 * HWc + pb };
    const int segbc[3] = { 81, 64, 64 };
    const float* segf[2] = {
        lastfeat + (size_t)b * 64 * HWc + pb,
        lastflow + (size_t)b * 4  * HWc + pb };
    const int segfc[2] = { 64, 4 };

    int g = 0;
    for (int s = 0; s < 3; s++) {
        const bf16* ip = segb[s];
        int n = segbc[s];
        for (int i = 0; i < n; i++) {
            bf162 xv = *(const bf162*)(ip + i * HWc);
            float x0 = to_f(xv.x), x1v = to_f(xv.y);
#pragma unroll
            for (int j = 0; j < 16; j++) {
                float wv = wl[j * 277 + g];
                acc[j][0] += wv * x0;
                acc[j][1] += wv * x1v;
            }
            g++;
        }
    }
    for (int s = 0; s < 2; s++) {
        const float* ip = segf[s];
        int n = segfc[s];
        for (int i = 0; i < n; i++) {
            float2 xv = *(const float2*)(ip + i * HWc);
#pragma unroll
            for (int j = 0; j < 16; j++) {
                float wv = wl[j * 277 + g];
                acc[j][0] += wv * xv.x;
                acc[j][1] += wv * xv.y;
            }
            g++;
        }
    }

    bf16* op = out + ((size_t)b * 160 + o0) * HWc + pb;
#pragma unroll
    for (int j = 0; j < 16; j++) {
        float a0 = acc[j][0], a1 = acc[j][1];
        a0 = (a0 > 0.f) ? a0 : 0.1f * a0;
        a1 = (a1 > 0.f) ? a1 : 0.1f * a1;
        store2(op + j * HWc, a0, a1);
    }
}

// ---------------------------------------------------------------------------
// generic 3x3 conv, pad=1. Each thread: 2x2 output px x OCH outputs.
// Weights staged in LDS in 16-input-channel chunks (broadcast reads).
// ---------------------------------------------------------------------------
template <int CIN, int COUT, int OCH, bool RELU, typename TIN, typename TOUT>
__global__ __launch_bounds__(256) void conv3_kernel(
    const TIN* __restrict__ in, const float* __restrict__ w,
    const float* __restrict__ bias, TOUT* __restrict__ out) {
    const int ICH = 16;
    __shared__ float wl[OCH * ICH * 9];

    int o0 = blockIdx.y * OCH;
    int t = blockIdx.x * 256 + threadIdx.x;   // 2x2 tile index
    const int W2 = Ww / 2, H2 = Hh / 2;
    int txi = t % W2;
    int rest = t / W2;
    int tyi = rest % H2;
    int b = rest / H2;
    int x0 = txi * 2, y0 = tyi * 2;

    float acc[OCH][4];
#pragma unroll
    for (int j = 0; j < OCH; j++) {
        float bv = bias[o0 + j];
        acc[j][0] = bv; acc[j][1] = bv; acc[j][2] = bv; acc[j][3] = bv;
    }

    for (int i0 = 0; i0 < CIN; i0 += ICH) {
        __syncthreads();
        for (int idx = threadIdx.x; idx < OCH * ICH * 9; idx += 256) {
            int j = idx / (ICH * 9);
            int r = idx % (ICH * 9);
            wl[idx] = w[((o0 + j) * CIN + i0 + r / 9) * 9 + (r % 9)];
        }
        __syncthreads();

        for (int ii = 0; ii < ICH; ii++) {
            const TIN* ip = in + ((size_t)b * CIN + (i0 + ii)) * HWc;
            float nb[4][4];
#pragma unroll
            for (int r = 0; r < 4; r++) {
                int yy = y0 - 1 + r;
#pragma unroll
                for (int c = 0; c < 4; c++) {
                    int xx = x0 - 1 + c;
                    bool ok = (yy >= 0) && (yy < Hh) && (xx >= 0) && (xx < Ww);
                    nb[r][c] = ok ? to_f(ip[yy * Ww + xx]) : 0.0f;
                }
            }
#pragma unroll
            for (int j = 0; j < OCH; j++) {
                const float* wp = &wl[(j * ICH + ii) * 9];
#pragma unroll
                for (int ky = 0; ky < 3; ky++)
#pragma unroll
                    for (int kx = 0; kx < 3; kx++) {
                        float wv = wp[ky * 3 + kx];
                        acc[j][0] += wv * nb[ky][kx];
                        acc[j][1] += wv * nb[ky][kx + 1];
                        acc[j][2] += wv * nb[ky + 1][kx];
                        acc[j][3] += wv * nb[ky + 1][kx + 1];
                    }
            }
        }
    }

    TOUT* op = out + ((size_t)b * COUT + o0) * HWc + y0 * Ww + x0;
#pragma unroll
    for (int j = 0; j < OCH; j++) {
        float a0 = acc[j][0], a1 = acc[j][1], a2 = acc[j][2], a3 = acc[j][3];
        if (RELU) {
            a0 = (a0 > 0.f) ? a0 : 0.1f * a0;
            a1 = (a1 > 0.f) ? a1 : 0.1f * a1;
            a2 = (a2 > 0.f) ? a2 : 0.1f * a2;
            a3 = (a3 > 0.f) ? a3 : 0.1f * a3;
        }
        store2(op + j * HWc,      a0, a1);
        store2(op + j * HWc + Ww, a2, a3);
    }
}

// ---------------------------------------------------------------------------
// launch
// ---------------------------------------------------------------------------
extern "C" void kernel_launch(void* const* d_in, const int* in_sizes, int n_in,
                              void* d_out, int out_size, void* d_ws, size_t ws_size,
                              hipStream_t stream) {
    (void)in_sizes; (void)n_in; (void)out_size; (void)ws_size;

    const float* feat0     = (const float*)d_in[0];
    const float* feat1     = (const float*)d_in[1];
    const float* last_feat = (const float*)d_in[2];
    const float* last_flow = (const float*)d_in[3];
    const float* w1 = (const float*)d_in[4];  const float* b1 = (const float*)d_in[5];
    const float* w2 = (const float*)d_in[6];  const float* b2 = (const float*)d_in[7];
    const float* w3 = (const float*)d_in[8];  const float* b3 = (const float*)d_in[9];
    const float* w4 = (const float*)d_in[10]; const float* b4 = (const float*)d_in[11];
    const float* w5 = (const float*)d_in[12]; const float* b5 = (const float*)d_in[13];
    const float* w6 = (const float*)d_in[14]; const float* b6 = (const float*)d_in[15];

    // Workspace layout (byte offsets). High-water = 190,709,760 B (~191 MB).
    //   phase 1: acc0+acc1 fp32 [0 .. 127,795,200) ; f0h/f1h bf16 [127,795,200 .. 190,709,760)
    //   phase 2: vol bf16 [0 .. 39,813,120) ; x1 bf16 [39,813,120 .. 118,456,320)  (acc dead)
    //   phase 3: x2 bf16 [127,795,200 .. 190,709,760)  (f0h/f1h dead)
    //   phase 4: x3 bf16 [0 .. 55,050,240)             (vol/x1 dead)
    //   phase 5: x4 bf16 [55,050,240 .. 102,236,160)   (x2 dead)
    char* wsb = (char*)d_ws;
    float* acc0 = (float*)wsb;                    // 65*BHW f32
    float* acc1 = acc0 + (size_t)65 * BHW;        // 65*BHW f32
    bf16* f0h = (bf16*)(wsb + 127795200);         // 64*BHW bf16
    bf16* f1h = (bf16*)(wsb + 159252480);         // 64*BHW bf16
    bf16* vol = (bf16*)wsb;                       // 81*BHW bf16
    bf16* x1  = (bf16*)(wsb + 39813120);          // 160*BHW bf16
    bf16* x2  = (bf16*)(wsb + 127795200);         // 128*BHW bf16
    bf16* x3  = (bf16*)wsb;                       // 112*BHW bf16
    bf16* x4  = (bf16*)(wsb + 55050240);          // 96*BHW bf16

    float* flow_out = (float*)d_out;                    // B*4*HW
    float* feat_out = (float*)d_out + 4 * 4 * HWc;      // B*64*HW

    // zero the splat accumulators (acc0..acc1 contiguous fp32)
    {
        int n4 = 2 * 65 * BHW / 4;  // 7,987,200 float4s
        zero_kernel<<<(n4 + 255) / 256, 256, 0, stream>>>((float4*)acc0, n4);
    }

    splat_kernel<<<BHW / 256, 256, 0, stream>>>(feat0, last_flow, 0, 0.125f, acc0);
    splat_kernel<<<BHW / 256, 256, 0, stream>>>(feat1, last_flow, 2, 0.125f, acc1);
    normconv_kernel<<<dim3(BHW / 256, 2), 256, 0, stream>>>(acc0, acc1, f0h, f1h);
    corr_kernel<<<BHW / 256, 256, 0, stream>>>(f0h, f1h, vol);

    conv1_kernel<<<dim3(BHW / 512, 10), 256, 0, stream>>>(
        vol, f0h, f1h, last_feat, last_flow, w1, b1, x1);

    const int tiles = Bb * (Hh / 2) * (Ww / 2) / 256; // 240
    conv3_kernel<160, 128, 16, true,  bf16, bf16 ><<<dim3(tiles, 8), 256, 0, stream>>>(x1, w2, b2, x2);
    conv3_kernel<128, 112, 16, true,  bf16, bf16 ><<<dim3(tiles, 7), 256, 0, stream>>>(x2, w3, b3, x3);
    conv3_kernel<112,  96, 16, true,  bf16, bf16 ><<<dim3(tiles, 6), 256, 0, stream>>>(x3, w4, b4, x4);
    conv3_kernel< 96,  64, 16, true,  bf16, float><<<dim3(tiles, 4), 256, 0, stream>>>(x4, w5, b5, feat_out);
    conv3_kernel< 64,   4,  4, false, float, float><<<dim3(tiles, 1), 256, 0, stream>>>(feat_out, w6, b6, flow_out);
}